// Round 1
// baseline (202.826 us; speedup 1.0000x reference)
//
#include <hip/hip_runtime.h>
#include <hip/hip_bf16.h>

#define NN 512
#define DD 128

typedef __bf16 bf16x8 __attribute__((ext_vector_type(8)));
typedef __bf16 bf16x4 __attribute__((ext_vector_type(4)));
typedef float f32x4 __attribute__((ext_vector_type(4)));

static __device__ __forceinline__ f32x4 mfma16(bf16x8 a, bf16x8 b, f32x4 c) {
  return __builtin_amdgcn_mfma_f32_16x16x32_bf16(a, b, c, 0, 0, 0);
}

// ---------------- phase 0a: weight transposes to bf16 ----------------
// w1t[e][k] = msg_w1[128+k][e]  (w1_e transposed), w2t[n][k] = msg_w2[k][n]
__global__ void k_prep(const float* __restrict__ msg_w1,
                       const float* __restrict__ msg_w2,
                       __bf16* __restrict__ w1t, __bf16* __restrict__ w2t) {
  int t = blockIdx.x * 256 + threadIdx.x;   // 16384 total
  int e = t >> 7, k = t & 127;
  w1t[e * 128 + k] = (__bf16)msg_w1[(128 + k) * 128 + e];
  w2t[e * 128 + k] = (__bf16)msg_w2[k * 128 + e];
}

// ---------------- phase 0b: hjp[j][e] = h[j]@w1_h + b1 ----------------
__global__ void k_hjp(const float* __restrict__ h, const float* __restrict__ w1,
                      const float* __restrict__ b1, float* __restrict__ hjp) {
  __shared__ float hr[128];
  int j = blockIdx.x, t = threadIdx.x;
  hr[t] = h[j * 128 + t];
  __syncthreads();
  float acc = b1[t];
  #pragma unroll 8
  for (int k = 0; k < 128; k++) acc += hr[k] * w1[k * 128 + t];
  hjp[j * 128 + t] = acc;
}

// ---------------- phase 1: fused msgs + mask + agg-partial ----------------
// LDS: [0,34816) w1t[128][136] bf16 | [34816,69632) w2t[128][136] bf16
//      [69632,139264) per-wave S[32][136] bf16, reused as f32 reduce bufs
#define LDS_BYTES 139264

__global__ __launch_bounds__(512, 2) void k_main(
    const float* __restrict__ rel, const int* __restrict__ emask,
    const float* __restrict__ hjp, const __bf16* __restrict__ w1t_g,
    const __bf16* __restrict__ w2t_g, const float* __restrict__ b2,
    float* __restrict__ partial) {
  extern __shared__ char smem[];
  __bf16* w1t = (__bf16*)smem;
  __bf16* w2t = w1t + 128 * 136;
  const int tid = threadIdx.x;
  const int wave = tid >> 6;
  const int lane = tid & 63;
  const int l15 = lane & 15;
  const int q = lane >> 4;
  __bf16* S = w2t + 128 * 136 + wave * (32 * 136);

  // stage weights into padded LDS (pad 8 bf16 per row: row stride 272B)
  #pragma unroll
  for (int t0 = 0; t0 < 4; t0++) {
    int t = tid + t0 * 512;
    int e = t >> 4, k8 = (t & 15) << 3;
    *(bf16x8*)(w1t + e * 136 + k8) = *(const bf16x8*)(w1t_g + e * 128 + k8);
    *(bf16x8*)(w2t + e * 136 + k8) = *(const bf16x8*)(w2t_g + e * 128 + k8);
  }
  __syncthreads();

  const int it = blockIdx.x >> 4;
  const int jc = blockIdx.x & 15;
  const int i0 = it * 32;

  float b2v[8];
  #pragma unroll
  for (int cf = 0; cf < 8; cf++) b2v[cf] = b2[cf * 16 + l15];

  f32x4 agg[8][2];
  #pragma unroll
  for (int cf = 0; cf < 8; cf++)
    #pragma unroll
    for (int rf = 0; rf < 2; rf++) {
      f32x4 z = {0.f, 0.f, 0.f, 0.f};
      agg[cf][rf] = z;
    }

  const int jbase = jc * 32 + wave * 4;
  for (int jj = 0; jj < 4; jj++) {
    const int j = jbase + jj;

    // load 32 rel rows (this wave's B-operand): B[k][i] = rel[j][i0+i][k]
    bf16x8 bfr[2][4];
    #pragma unroll
    for (int rf = 0; rf < 2; rf++) {
      const float* rowp = rel + ((size_t)j * NN + i0 + rf * 16 + l15) * DD + q * 8;
      #pragma unroll
      for (int kc = 0; kc < 4; kc++) {
        f32x4 x0 = *(const f32x4*)(rowp + kc * 32);
        f32x4 x1 = *(const f32x4*)(rowp + kc * 32 + 4);
        bf16x8 bb;
        bb[0] = (__bf16)x0[0]; bb[1] = (__bf16)x0[1];
        bb[2] = (__bf16)x0[2]; bb[3] = (__bf16)x0[3];
        bb[4] = (__bf16)x1[0]; bb[5] = (__bf16)x1[1];
        bb[6] = (__bf16)x1[2]; bb[7] = (__bf16)x1[3];
        bfr[rf][kc] = bb;
      }
    }

    // GEMM1 transposed: PRE^T[e,i] = sum_k w1t[e][k] * rel[j][i][k]
    f32x4 acc1[8][2];
    #pragma unroll
    for (int ef = 0; ef < 8; ef++)
      #pragma unroll
      for (int rf = 0; rf < 2; rf++) {
        f32x4 z = {0.f, 0.f, 0.f, 0.f};
        acc1[ef][rf] = z;
      }
    #pragma unroll
    for (int kc = 0; kc < 4; kc++) {
      #pragma unroll
      for (int ef = 0; ef < 8; ef++) {
        bf16x8 a = *(const bf16x8*)(w1t + (ef * 16 + l15) * 136 + kc * 32 + q * 8);
        acc1[ef][0] = mfma16(a, bfr[0][kc], acc1[ef][0]);
        acc1[ef][1] = mfma16(a, bfr[1][kc], acc1[ef][1]);
      }
    }

    // silu(pre + hjp[j]) -> S[i][e] bf16 ; C^T layout: col=i=rf*16+l15, row=e=ef*16+4q+r
    const float* hj = hjp + (size_t)j * DD + q * 4;
    #pragma unroll
    for (int ef = 0; ef < 8; ef++) {
      f32x4 hv = *(const f32x4*)(hj + ef * 16);
      #pragma unroll
      for (int rf = 0; rf < 2; rf++) {
        bf16x4 pk;
        #pragma unroll
        for (int r = 0; r < 4; r++) {
          float x = acc1[ef][rf][r] + hv[r];
          pk[r] = (__bf16)(x / (1.f + __expf(-x)));
        }
        *(bf16x4*)(S + (rf * 16 + l15) * 136 + ef * 16 + q * 4) = pk;
      }
    }

    // GEMM2: M[i,d] = sum_e S[i][e] * w2[e][d] + b2[d]
    f32x4 acc2[8][2];
    #pragma unroll
    for (int cf = 0; cf < 8; cf++)
      #pragma unroll
      for (int rf = 0; rf < 2; rf++) {
        f32x4 z = {b2v[cf], b2v[cf], b2v[cf], b2v[cf]};
        acc2[cf][rf] = z;
      }
    #pragma unroll
    for (int kc = 0; kc < 4; kc++) {
      bf16x8 a0 = *(const bf16x8*)(S + l15 * 136 + kc * 32 + q * 8);
      bf16x8 a1 = *(const bf16x8*)(S + (16 + l15) * 136 + kc * 32 + q * 8);
      #pragma unroll
      for (int cf = 0; cf < 8; cf++) {
        bf16x8 wb = *(const bf16x8*)(w2t + (cf * 16 + l15) * 136 + kc * 32 + q * 8);
        acc2[cf][0] = mfma16(a0, wb, acc2[cf][0]);
        acc2[cf][1] = mfma16(a1, wb, acc2[cf][1]);
      }
    }

    // masked accumulate: agg[i][d] += edge_mask[j][i] * M[i][d]
    #pragma unroll
    for (int rf = 0; rf < 2; rf++) {
      int4 mv = *(const int4*)(emask + (size_t)j * NN + i0 + rf * 16 + q * 4);
      float m0 = mv.x ? 1.f : 0.f, m1 = mv.y ? 1.f : 0.f;
      float m2 = mv.z ? 1.f : 0.f, m3 = mv.w ? 1.f : 0.f;
      #pragma unroll
      for (int cf = 0; cf < 8; cf++) {
        agg[cf][rf][0] += m0 * acc2[cf][rf][0];
        agg[cf][rf][1] += m1 * acc2[cf][rf][1];
        agg[cf][rf][2] += m2 * acc2[cf][rf][2];
        agg[cf][rf][3] += m3 * acc2[cf][rf][3];
      }
    }
  }

  // cross-wave reduction: two 16-row halves, per-wave f32 bufs [16][132]
  float* fbase = (float*)(smem + 69632);
  float* fb = fbase + wave * (16 * 132);
  #pragma unroll
  for (int rf = 0; rf < 2; rf++) {
    __syncthreads();   // all waves done with S-as-bf16 (and prev round reads)
    #pragma unroll
    for (int cf = 0; cf < 8; cf++)
      #pragma unroll
      for (int r = 0; r < 4; r++)
        fb[(q * 4 + r) * 132 + cf * 16 + l15] = agg[cf][rf][r];
    __syncthreads();
    int i16 = tid >> 5;
    int d4 = (tid & 31) << 2;
    f32x4 s = {0.f, 0.f, 0.f, 0.f};
    #pragma unroll
    for (int w = 0; w < 8; w++) {
      f32x4 v = *(const f32x4*)(fbase + w * (16 * 132) + i16 * 132 + d4);
      s += v;
    }
    *(f32x4*)(partial + ((size_t)jc * NN + i0 + rf * 16 + i16) * DD + d4) = s;
  }
}

// ---------------- phase 2: reduce partials + update MLP + LayerNorm ----------------
__global__ void k_update(const float* __restrict__ h, const float* __restrict__ partial,
                         const float* __restrict__ uw1, const float* __restrict__ ub1,
                         const float* __restrict__ uw2, const float* __restrict__ ub2,
                         const float* __restrict__ g, const float* __restrict__ bb,
                         float* __restrict__ out) {
  __shared__ float uin[256];
  __shared__ float zl[128];
  __shared__ float ss[4];
  int i = blockIdx.x, t = threadIdx.x;
  float hv = h[i * 128 + t];
  float a = 0.f;
  #pragma unroll
  for (int c = 0; c < 16; c++) a += partial[((size_t)c * NN + i) * DD + t];
  uin[t] = hv;
  uin[128 + t] = a;
  __syncthreads();
  float z = ub1[t];
  #pragma unroll 8
  for (int k = 0; k < 256; k++) z += uin[k] * uw1[k * 128 + t];
  z = z / (1.f + __expf(-z));
  zl[t] = z;
  __syncthreads();
  float dl = ub2[t];
  #pragma unroll 8
  for (int k = 0; k < 128; k++) dl += zl[k] * uw2[k * 128 + t];
  float x = hv + dl;
  float s1 = x, s2 = x * x;
  #pragma unroll
  for (int off = 32; off > 0; off >>= 1) {
    s1 += __shfl_down(s1, off, 64);
    s2 += __shfl_down(s2, off, 64);
  }
  if ((t & 63) == 0) { ss[(t >> 6) * 2] = s1; ss[(t >> 6) * 2 + 1] = s2; }
  __syncthreads();
  s1 = ss[0] + ss[2];
  s2 = ss[1] + ss[3];
  float mu = s1 * (1.f / 128.f);
  float var = s2 * (1.f / 128.f) - mu * mu;
  out[i * 128 + t] = (x - mu) * rsqrtf(var + 1e-5f) * g[t] + bb[t];
}

extern "C" void kernel_launch(void* const* d_in, const int* in_sizes, int n_in,
                              void* d_out, int out_size, void* d_ws, size_t ws_size,
                              hipStream_t stream) {
  const float* h      = (const float*)d_in[0];
  const float* rel    = (const float*)d_in[1];
  const int*   emask  = (const int*)d_in[2];
  const float* msg_w1 = (const float*)d_in[3];
  const float* msg_b1 = (const float*)d_in[4];
  const float* msg_w2 = (const float*)d_in[5];
  const float* msg_b2 = (const float*)d_in[6];
  const float* upd_w1 = (const float*)d_in[7];
  const float* upd_b1 = (const float*)d_in[8];
  const float* upd_w2 = (const float*)d_in[9];
  const float* upd_b2 = (const float*)d_in[10];
  const float* ln_g   = (const float*)d_in[11];
  const float* ln_b   = (const float*)d_in[12];
  float* out = (float*)d_out;

  char* ws = (char*)d_ws;
  float*  hjp     = (float*)ws;                       // 262144 B
  __bf16* w1t     = (__bf16*)(ws + 262144);           // 32768 B
  __bf16* w2t     = (__bf16*)(ws + 262144 + 32768);   // 32768 B
  float*  partial = (float*)(ws + 262144 + 65536);    // 16*512*128*4 = 4 MiB

  k_prep<<<64, 256, 0, stream>>>(msg_w1, msg_w2, w1t, w2t);
  k_hjp<<<512, 128, 0, stream>>>(h, msg_w1, msg_b1, hjp);
  hipFuncSetAttribute((const void*)k_main,
                      hipFuncAttributeMaxDynamicSharedMemorySize, LDS_BYTES);
  k_main<<<256, 512, LDS_BYTES, stream>>>(rel, emask, hjp, w1t, w2t, msg_b2, partial);
  k_update<<<512, 128, 0, stream>>>(h, partial, upd_w1, upd_b1, upd_w2, upd_b2,
                                    ln_g, ln_b, out);
}

// Round 2
// 158.209 us; speedup vs baseline: 1.2820x; 1.2820x over previous
//
#include <hip/hip_runtime.h>
#include <hip/hip_bf16.h>

#define NN 512
#define DD 128

typedef __bf16 bf16x8 __attribute__((ext_vector_type(8)));
typedef __bf16 bf16x4 __attribute__((ext_vector_type(4)));
typedef float f32x4 __attribute__((ext_vector_type(4)));

static __device__ __forceinline__ f32x4 mfma16(bf16x8 a, bf16x8 b, f32x4 c) {
  return __builtin_amdgcn_mfma_f32_16x16x32_bf16(a, b, c, 0, 0, 0);
}

// ---------------- phase 0a: weight transposes to bf16 ----------------
// w1t[e][k] = msg_w1[128+k][e]  (w1_e transposed), w2t[n][k] = msg_w2[k][n]
__global__ void k_prep(const float* __restrict__ msg_w1,
                       const float* __restrict__ msg_w2,
                       __bf16* __restrict__ w1t, __bf16* __restrict__ w2t) {
  int t = blockIdx.x * 256 + threadIdx.x;   // 16384 total
  int e = t >> 7, k = t & 127;
  w1t[e * 128 + k] = (__bf16)msg_w1[(128 + k) * 128 + e];
  w2t[e * 128 + k] = (__bf16)msg_w2[k * 128 + e];
}

// ---------------- phase 0b: hjp[j][e] = h[j]@w1_h + b1 ----------------
__global__ void k_hjp(const float* __restrict__ h, const float* __restrict__ w1,
                      const float* __restrict__ b1, float* __restrict__ hjp) {
  __shared__ float hr[128];
  int j = blockIdx.x, t = threadIdx.x;
  hr[t] = h[j * 128 + t];
  __syncthreads();
  float acc = b1[t];
  #pragma unroll 8
  for (int k = 0; k < 128; k++) acc += hr[k] * w1[k * 128 + t];
  hjp[j * 128 + t] = acc;
}

// ---------------- phase 0c: cnt[i] = sum_j edge_mask[j][i] ----------------
__global__ void k_cnt(const int* __restrict__ emask, float* __restrict__ cnt) {
  int col = blockIdx.x * 128 + threadIdx.x;
  int s = 0;
  #pragma unroll 8
  for (int j = 0; j < NN; j++) s += emask[j * NN + col] ? 1 : 0;
  cnt[col] = (float)s;
}

// ---------------- phase 1: fused msgs + mask + agg-partial ----------------
// LDS: [0,34816) w1t[128][136] bf16 | [34816,69632) w2t[128][136] bf16
//      [69632,139264) per-wave S[32][136] bf16, reused as f32 reduce bufs
#define LDS_BYTES 139264

// launch_bounds(512,1): block-fit still caps VGPR at 256 (8 waves/block must
// co-reside -> 2 waves/SIMD); (512,2) made the allocator clamp to 128 and
// spill ~460KB/block (R1: WRITE_SIZE 117MB vs 4MB programmed).
__global__ __launch_bounds__(512, 1) void k_main(
    const float* __restrict__ rel, const int* __restrict__ emask,
    const float* __restrict__ hjp, const __bf16* __restrict__ w1t_g,
    const __bf16* __restrict__ w2t_g, float* __restrict__ partial) {
  extern __shared__ char smem[];
  __bf16* w1t = (__bf16*)smem;
  __bf16* w2t = w1t + 128 * 136;
  const int tid = threadIdx.x;
  const int wave = tid >> 6;
  const int lane = tid & 63;
  const int l15 = lane & 15;
  const int q = lane >> 4;
  __bf16* S = w2t + 128 * 136 + wave * (32 * 136);

  // stage weights into padded LDS (pad 8 bf16 per row: row stride 272B)
  #pragma unroll
  for (int t0 = 0; t0 < 4; t0++) {
    int t = tid + t0 * 512;
    int e = t >> 4, k8 = (t & 15) << 3;
    *(bf16x8*)(w1t + e * 136 + k8) = *(const bf16x8*)(w1t_g + e * 128 + k8);
    *(bf16x8*)(w2t + e * 136 + k8) = *(const bf16x8*)(w2t_g + e * 128 + k8);
  }
  __syncthreads();

  const int it = blockIdx.x >> 4;
  const int jc = blockIdx.x & 15;
  const int i0 = it * 32;

  // agg accumulates GEMM2 output directly across the whole j loop
  f32x4 agg[8][2];
  #pragma unroll
  for (int cf = 0; cf < 8; cf++)
    #pragma unroll
    for (int rf = 0; rf < 2; rf++) {
      f32x4 z = {0.f, 0.f, 0.f, 0.f};
      agg[cf][rf] = z;
    }

  const int jbase = jc * 32 + wave * 4;
  for (int jj = 0; jj < 4; jj++) {
    const int j = jbase + jj;

    // load 32 rel rows (this wave's B-operand): B[k][i] = rel[j][i0+i][k]
    bf16x8 bfr[2][4];
    #pragma unroll
    for (int rf = 0; rf < 2; rf++) {
      const float* rowp = rel + ((size_t)j * NN + i0 + rf * 16 + l15) * DD + q * 8;
      #pragma unroll
      for (int kc = 0; kc < 4; kc++) {
        f32x4 x0 = *(const f32x4*)(rowp + kc * 32);
        f32x4 x1 = *(const f32x4*)(rowp + kc * 32 + 4);
        bf16x8 bb;
        bb[0] = (__bf16)x0[0]; bb[1] = (__bf16)x0[1];
        bb[2] = (__bf16)x0[2]; bb[3] = (__bf16)x0[3];
        bb[4] = (__bf16)x1[0]; bb[5] = (__bf16)x1[1];
        bb[6] = (__bf16)x1[2]; bb[7] = (__bf16)x1[3];
        bfr[rf][kc] = bb;
      }
    }

    // GEMM1 transposed: PRE^T[e,i] = sum_k w1t[e][k] * rel[j][i][k]
    f32x4 acc1[8][2];
    #pragma unroll
    for (int ef = 0; ef < 8; ef++)
      #pragma unroll
      for (int rf = 0; rf < 2; rf++) {
        f32x4 z = {0.f, 0.f, 0.f, 0.f};
        acc1[ef][rf] = z;
      }
    #pragma unroll
    for (int kc = 0; kc < 4; kc++) {
      #pragma unroll
      for (int ef = 0; ef < 8; ef++) {
        bf16x8 a = *(const bf16x8*)(w1t + (ef * 16 + l15) * 136 + kc * 32 + q * 8);
        acc1[ef][0] = mfma16(a, bfr[0][kc], acc1[ef][0]);
        acc1[ef][1] = mfma16(a, bfr[1][kc], acc1[ef][1]);
      }
    }

    // mask[j, i] per lane: C^T layout col = i = rf*16 + l15 (lane-resident)
    float m0s = emask[(size_t)j * NN + i0 + l15] ? 1.f : 0.f;
    float m1s = emask[(size_t)j * NN + i0 + 16 + l15] ? 1.f : 0.f;

    // S[i][e] = mask * silu(pre + hjp[j])  (bf16)
    const float* hj = hjp + (size_t)j * DD + q * 4;
    #pragma unroll
    for (int ef = 0; ef < 8; ef++) {
      f32x4 hv = *(const f32x4*)(hj + ef * 16);
      #pragma unroll
      for (int rf = 0; rf < 2; rf++) {
        float ms = rf ? m1s : m0s;
        bf16x4 pk;
        #pragma unroll
        for (int r = 0; r < 4; r++) {
          float x = acc1[ef][rf][r] + hv[r];
          pk[r] = (__bf16)(ms * x / (1.f + __expf(-x)));
        }
        *(bf16x4*)(S + (rf * 16 + l15) * 136 + ef * 16 + q * 4) = pk;
      }
    }

    // GEMM2 accumulates straight into agg: agg[i,d] += S[i,:] @ w2[:,d]
    #pragma unroll
    for (int kc = 0; kc < 4; kc++) {
      bf16x8 a0 = *(const bf16x8*)(S + l15 * 136 + kc * 32 + q * 8);
      bf16x8 a1 = *(const bf16x8*)(S + (16 + l15) * 136 + kc * 32 + q * 8);
      #pragma unroll
      for (int cf = 0; cf < 8; cf++) {
        bf16x8 wb = *(const bf16x8*)(w2t + (cf * 16 + l15) * 136 + kc * 32 + q * 8);
        agg[cf][0] = mfma16(a0, wb, agg[cf][0]);
        agg[cf][1] = mfma16(a1, wb, agg[cf][1]);
      }
    }
  }

  // cross-wave reduction: two 16-row halves, per-wave f32 bufs [16][132]
  float* fbase = (float*)(smem + 69632);
  float* fb = fbase + wave * (16 * 132);
  #pragma unroll
  for (int rf = 0; rf < 2; rf++) {
    __syncthreads();   // all waves done with S-as-bf16 (and prev round reads)
    #pragma unroll
    for (int cf = 0; cf < 8; cf++)
      #pragma unroll
      for (int r = 0; r < 4; r++)
        fb[(q * 4 + r) * 132 + cf * 16 + l15] = agg[cf][rf][r];
    __syncthreads();
    int i16 = tid >> 5;
    int d4 = (tid & 31) << 2;
    f32x4 s = {0.f, 0.f, 0.f, 0.f};
    #pragma unroll
    for (int w = 0; w < 8; w++) {
      f32x4 v = *(const f32x4*)(fbase + w * (16 * 132) + i16 * 132 + d4);
      s += v;
    }
    *(f32x4*)(partial + ((size_t)jc * NN + i0 + rf * 16 + i16) * DD + d4) = s;
  }
}

// ---------------- phase 2: reduce partials + update MLP + LayerNorm ----------------
__global__ void k_update(const float* __restrict__ h, const float* __restrict__ partial,
                         const float* __restrict__ b2, const float* __restrict__ cnt,
                         const float* __restrict__ uw1, const float* __restrict__ ub1,
                         const float* __restrict__ uw2, const float* __restrict__ ub2,
                         const float* __restrict__ g, const float* __restrict__ bb,
                         float* __restrict__ out) {
  __shared__ float uin[256];
  __shared__ float zl[128];
  __shared__ float ss[4];
  int i = blockIdx.x, t = threadIdx.x;
  float hv = h[i * 128 + t];
  float a = cnt[i] * b2[t];
  #pragma unroll
  for (int c = 0; c < 16; c++) a += partial[((size_t)c * NN + i) * DD + t];
  uin[t] = hv;
  uin[128 + t] = a;
  __syncthreads();
  float z = ub1[t];
  #pragma unroll 8
  for (int k = 0; k < 256; k++) z += uin[k] * uw1[k * 128 + t];
  z = z / (1.f + __expf(-z));
  zl[t] = z;
  __syncthreads();
  float dl = ub2[t];
  #pragma unroll 8
  for (int k = 0; k < 128; k++) dl += zl[k] * uw2[k * 128 + t];
  float x = hv + dl;
  float s1 = x, s2 = x * x;
  #pragma unroll
  for (int off = 32; off > 0; off >>= 1) {
    s1 += __shfl_down(s1, off, 64);
    s2 += __shfl_down(s2, off, 64);
  }
  if ((t & 63) == 0) { ss[(t >> 6) * 2] = s1; ss[(t >> 6) * 2 + 1] = s2; }
  __syncthreads();
  s1 = ss[0] + ss[2];
  s2 = ss[1] + ss[3];
  float mu = s1 * (1.f / 128.f);
  float var = s2 * (1.f / 128.f) - mu * mu;
  out[i * 128 + t] = (x - mu) * rsqrtf(var + 1e-5f) * g[t] + bb[t];
}

extern "C" void kernel_launch(void* const* d_in, const int* in_sizes, int n_in,
                              void* d_out, int out_size, void* d_ws, size_t ws_size,
                              hipStream_t stream) {
  const float* h      = (const float*)d_in[0];
  const float* rel    = (const float*)d_in[1];
  const int*   emask  = (const int*)d_in[2];
  const float* msg_w1 = (const float*)d_in[3];
  const float* msg_b1 = (const float*)d_in[4];
  const float* msg_w2 = (const float*)d_in[5];
  const float* msg_b2 = (const float*)d_in[6];
  const float* upd_w1 = (const float*)d_in[7];
  const float* upd_b1 = (const float*)d_in[8];
  const float* upd_w2 = (const float*)d_in[9];
  const float* upd_b2 = (const float*)d_in[10];
  const float* ln_g   = (const float*)d_in[11];
  const float* ln_b   = (const float*)d_in[12];
  float* out = (float*)d_out;

  char* ws = (char*)d_ws;
  float*  hjp     = (float*)ws;                        // 262144 B
  __bf16* w1t     = (__bf16*)(ws + 262144);            // 32768 B
  __bf16* w2t     = (__bf16*)(ws + 262144 + 32768);    // 32768 B
  float*  cnt     = (float*)(ws + 262144 + 65536);     // 2048 B
  float*  partial = (float*)(ws + 262144 + 65536 + 4096); // 4 MiB

  k_prep<<<64, 256, 0, stream>>>(msg_w1, msg_w2, w1t, w2t);
  k_hjp<<<512, 128, 0, stream>>>(h, msg_w1, msg_b1, hjp);
  k_cnt<<<4, 128, 0, stream>>>(emask, cnt);
  hipFuncSetAttribute((const void*)k_main,
                      hipFuncAttributeMaxDynamicSharedMemorySize, LDS_BYTES);
  k_main<<<256, 512, LDS_BYTES, stream>>>(rel, emask, hjp, w1t, w2t, partial);
  k_update<<<512, 128, 0, stream>>>(h, partial, msg_b2, cnt, upd_w1, upd_b1,
                                    upd_w2, upd_b2, ln_g, ln_b, out);
}